// Round 2
// baseline (317.719 us; speedup 1.0000x reference)
//
#include <hip/hip_runtime.h>
#include <math.h>

#define BB 4
#define CC 64
#define CI 32
#define NN 4096
#define EPS 1e-5f

#define PROJ_SZ (BB * CI * NN) /* 524288 elems */

typedef __attribute__((ext_vector_type(8))) short bf16x8;
typedef __attribute__((ext_vector_type(4))) float f32x4;

__device__ __forceinline__ ushort f2bf(float f) {
    uint u = __builtin_bit_cast(uint, f);
    u += 0x7FFFu + ((u >> 16) & 1u);          // round-to-nearest-even
    return (ushort)(u >> 16);
}
__device__ __forceinline__ float bf2f(ushort h) {
    uint u = (uint)h << 16;
    return __builtin_bit_cast(float, u);
}
__device__ __forceinline__ uint pk2(float a, float b) {
    return (uint)f2bf(a) | ((uint)f2bf(b) << 16);
}
__device__ __forceinline__ bf16x8 mk8(uint a, uint b, uint c, uint d) {
    uint4 u; u.x = a; u.y = b; u.z = c; u.w = d;
    return __builtin_bit_cast(bf16x8, u);
}

// ---------------------------------------------------------------------------
// proj: BN -> 1x1 conv, emits bf16.
// job 0: g(x1)->g1 [b][c][n] ; job 1: g(x2)->g2 [b][c][n]
// job 2: th(x1)->thT [b][n][CI] ; job 3: ph(x2)->phT [b][m][CI]
// ---------------------------------------------------------------------------
__global__ __launch_bounds__(256) void proj_kernel(
    const float* __restrict__ x1, const float* __restrict__ x2,
    const float* __restrict__ gw, const float* __restrict__ gb,
    const float* __restrict__ gga, const float* __restrict__ gbe,
    const float* __restrict__ gmu, const float* __restrict__ gva,
    const float* __restrict__ tw, const float* __restrict__ tb,
    const float* __restrict__ tga, const float* __restrict__ tbe,
    const float* __restrict__ tmu, const float* __restrict__ tva,
    const float* __restrict__ pw, const float* __restrict__ pb,
    const float* __restrict__ pga, const float* __restrict__ pbe,
    const float* __restrict__ pmu, const float* __restrict__ pva,
    ushort* __restrict__ g1o, ushort* __restrict__ g2o,
    ushort* __restrict__ thTo, ushort* __restrict__ phTo)
{
    int job = blockIdx.y;
    const float* src = (job == 0 || job == 2) ? x1 : x2;
    const float *w, *bia, *ga, *be, *mu, *va;
    if (job <= 1)      { w = gw; bia = gb; ga = gga; be = gbe; mu = gmu; va = gva; }
    else if (job == 2) { w = tw; bia = tb; ga = tga; be = tbe; mu = tmu; va = tva; }
    else               { w = pw; bia = pb; ga = pga; be = pbe; mu = pmu; va = pva; }

    __shared__ __align__(16) float s_w[CI][CC];
    __shared__ float s_scale[CC], s_shift[CC], s_b[CI];
    int t = threadIdx.x;
    if (t < CC) {
        float sc = ga[t] / sqrtf(va[t] + EPS);
        s_scale[t] = sc;
        s_shift[t] = be[t] - mu[t] * sc;
    }
    if (t >= CC && t < CC + CI) s_b[t - CC] = bia[t - CC];
    for (int i = t; i < CI * CC; i += 256) s_w[i / CC][i % CC] = w[i];
    __syncthreads();

    int bn = blockIdx.x * 256 + t;
    int b = bn >> 12, n = bn & (NN - 1);
    const float* xp = src + ((size_t)b * CC) * NN + n;

    float acc[CI];
#pragma unroll
    for (int o = 0; o < CI; o++) acc[o] = s_b[o];

#pragma unroll 4
    for (int c4 = 0; c4 < CC / 4; c4++) {
        float xv0 = xp[(size_t)(c4 * 4 + 0) * NN] * s_scale[c4 * 4 + 0] + s_shift[c4 * 4 + 0];
        float xv1 = xp[(size_t)(c4 * 4 + 1) * NN] * s_scale[c4 * 4 + 1] + s_shift[c4 * 4 + 1];
        float xv2 = xp[(size_t)(c4 * 4 + 2) * NN] * s_scale[c4 * 4 + 2] + s_shift[c4 * 4 + 2];
        float xv3 = xp[(size_t)(c4 * 4 + 3) * NN] * s_scale[c4 * 4 + 3] + s_shift[c4 * 4 + 3];
#pragma unroll
        for (int o = 0; o < CI; o++) {
            float4 wv = *(const float4*)&s_w[o][c4 * 4];
            acc[o] += wv.x * xv0 + wv.y * xv1 + wv.z * xv2 + wv.w * xv3;
        }
    }

    if (job <= 1) {
        ushort* dp = (job ? g2o : g1o) + ((size_t)b * CI) * NN + n;
#pragma unroll
        for (int o = 0; o < CI; o++) dp[(size_t)o * NN] = f2bf(acc[o]);
    } else {
        uint u[16];
#pragma unroll
        for (int i = 0; i < 16; i++) u[i] = pk2(acc[2 * i], acc[2 * i + 1]);
        uint4* dp = (uint4*)((job == 2 ? thTo : phTo) + ((size_t)b * NN + n) * CI);
#pragma unroll
        for (int i = 0; i < 4; i++) {
            uint4 v; v.x = u[4 * i]; v.y = u[4 * i + 1]; v.z = u[4 * i + 2]; v.w = u[4 * i + 3];
            dp[i] = v;
        }
    }
}

// ---------------------------------------------------------------------------
// passA: block owns 64-m tile (wave w -> m-subtile w), streams an n-chunk.
// S[n,m] = sum_c th[c,n] ph[c,m] via mfma 16x16x32 (A=thT rows n, B=phT cols m).
// P = exp(S) in D-frags; z[m] partial via shfl_xor; PV uses the pi-permuted
// k-order so the B-operand is the lane's own packed P values (no LDS/shuffle).
// ---------------------------------------------------------------------------
__global__ __launch_bounds__(256) void passA_kernel(
    const ushort* __restrict__ thT, const ushort* __restrict__ phT,
    const ushort* __restrict__ g1,
    float* __restrict__ zpart, float* __restrict__ y1part, int NCH)
{
    const int t = threadIdx.x;
    const int wave = t >> 6, lane = t & 63;
    const int q = lane >> 4, lm = lane & 15;
    const int b = blockIdx.y, ch = blockIdx.z;
    const int m0 = blockIdx.x * 64;
    const int m = m0 + wave * 16 + lm;
    const size_t bN = (size_t)b * NN;

    // S B-frag (phT), invariant over n: B[k=c][j=m], j=lane&15, k=8q+e
    const bf16x8 bS = *(const bf16x8*)(phT + (bN + m) * CI + 8 * q);

    f32x4 acc0 = {0.f, 0.f, 0.f, 0.f};
    f32x4 acc1 = {0.f, 0.f, 0.f, 0.f};
    const f32x4 z4 = {0.f, 0.f, 0.f, 0.f};
    float zacc = 0.f;

    const int nchunk = NN / NCH;
    const int nbeg = ch * nchunk, nend = nbeg + nchunk;
    const ushort* g1b = g1 + (size_t)b * CI * NN;

    for (int ns = nbeg; ns < nend; ns += 64) {
        // A-frags (thT): row i=n=ns+16s+lm, k=c=8q+e -> one 16B load each
        const ushort* ta = thT + (bN + ns + lm) * CI + 8 * q;
        bf16x8 a0 = *(const bf16x8*)(ta);
        bf16x8 a1 = *(const bf16x8*)(ta + 16 * CI);
        bf16x8 a2 = *(const bf16x8*)(ta + 32 * CI);
        bf16x8 a3 = *(const bf16x8*)(ta + 48 * CI);
        f32x4 d0 = __builtin_amdgcn_mfma_f32_16x16x32_bf16(a0, bS, z4, 0, 0, 0);
        f32x4 d1 = __builtin_amdgcn_mfma_f32_16x16x32_bf16(a1, bS, z4, 0, 0, 0);
        f32x4 d2 = __builtin_amdgcn_mfma_f32_16x16x32_bf16(a2, bS, z4, 0, 0, 0);
        f32x4 d3 = __builtin_amdgcn_mfma_f32_16x16x32_bf16(a3, bS, z4, 0, 0, 0);

        f32x4 p0, p1, p2, p3;
#pragma unroll
        for (int r = 0; r < 4; r++) {
            p0[r] = __expf(d0[r]); p1[r] = __expf(d1[r]);
            p2[r] = __expf(d2[r]); p3[r] = __expf(d3[r]);
        }

        // z[m] partial: sum over this n-step (16 local + lanes q=0..3 share m)
        float ls = ((p0[0] + p0[1]) + (p0[2] + p0[3]))
                 + ((p1[0] + p1[1]) + (p1[2] + p1[3]))
                 + ((p2[0] + p2[1]) + (p2[2] + p2[3]))
                 + ((p3[0] + p3[1]) + (p3[2] + p3[3]));
        ls += __shfl_xor(ls, 16);
        ls += __shfl_xor(ls, 32);
        zacc += ls;

        // pack P to bf16; with pi-permuted k-order these ARE the PV B-frags
        uint u00 = pk2(p0[0], p0[1]), u01 = pk2(p0[2], p0[3]);
        uint u10 = pk2(p1[0], p1[1]), u11 = pk2(p1[2], p1[3]);
        uint u20 = pk2(p2[0], p2[1]), u21 = pk2(p2[2], p2[3]);
        uint u30 = pk2(p3[0], p3[1]), u31 = pk2(p3[2], p3[3]);
        bf16x8 bP0 = mk8(u00, u01, u10, u11);   // k-block 0: n = ns+{4q+r, 16+4q+r}
        bf16x8 bP1 = mk8(u20, u21, u30, u31);   // k-block 1: n = ns+32+{...}

        // PV A-frags (g1) with the same pi k-order: two 8B loads per frag
        {
            const ushort* gp = g1b + (size_t)lm * NN + ns + 4 * q;
            uint2 lo = *(const uint2*)(gp);
            uint2 hi = *(const uint2*)(gp + 16);
            acc0 = __builtin_amdgcn_mfma_f32_16x16x32_bf16(mk8(lo.x, lo.y, hi.x, hi.y), bP0, acc0, 0, 0, 0);
            lo = *(const uint2*)(gp + 32);
            hi = *(const uint2*)(gp + 48);
            acc0 = __builtin_amdgcn_mfma_f32_16x16x32_bf16(mk8(lo.x, lo.y, hi.x, hi.y), bP1, acc0, 0, 0, 0);
        }
        {
            const ushort* gp = g1b + (size_t)(16 + lm) * NN + ns + 4 * q;
            uint2 lo = *(const uint2*)(gp);
            uint2 hi = *(const uint2*)(gp + 16);
            acc1 = __builtin_amdgcn_mfma_f32_16x16x32_bf16(mk8(lo.x, lo.y, hi.x, hi.y), bP0, acc1, 0, 0, 0);
            lo = *(const uint2*)(gp + 32);
            hi = *(const uint2*)(gp + 48);
            acc1 = __builtin_amdgcn_mfma_f32_16x16x32_bf16(mk8(lo.x, lo.y, hi.x, hi.y), bP1, acc1, 0, 0, 0);
        }
    }

    if (q == 0) zpart[((size_t)ch * BB + b) * NN + m] = zacc;

    float* yp = y1part + (((size_t)ch * BB + b) * CI) * NN + m;
#pragma unroll
    for (int r = 0; r < 4; r++) {
        yp[(size_t)(4 * q + r) * NN] = acc0[r];
        yp[(size_t)(16 + 4 * q + r) * NN] = acc1[r];
    }
}

// ---------------------------------------------------------------------------
// combine: rZ = 1/sum_ch z ; g2s[c][m] = bf16(g2[c][m] * rZ[m])
// ---------------------------------------------------------------------------
__global__ __launch_bounds__(256) void combine_kernel(
    const float* __restrict__ zpart, const ushort* __restrict__ g2,
    float* __restrict__ rZ, ushort* __restrict__ g2s, int NCH)
{
    int idx = blockIdx.x * 256 + threadIdx.x;   // b*NN + m
    float z = 0.f;
    for (int ch = 0; ch < NCH; ch++) z += zpart[(size_t)ch * BB * NN + idx];
    float r = 1.f / z;
    rZ[idx] = r;
    int b = idx >> 12, mm = idx & (NN - 1);
    const ushort* gp = g2 + (size_t)b * CI * NN + mm;
    ushort* gs = g2s + (size_t)b * CI * NN + mm;
#pragma unroll
    for (int c = 0; c < CI; c++) gs[(size_t)c * NN] = f2bf(bf2f(gp[(size_t)c * NN]) * r);
}

// ---------------------------------------------------------------------------
// passB: block owns 64-n tile (wave w -> n-subtile w), streams an m-chunk.
// S'[m,n] via mfma (A=phT rows m, B=thT cols n); y2 += g2s x P' (pi k-order).
// ---------------------------------------------------------------------------
__global__ __launch_bounds__(256) void passB_kernel(
    const ushort* __restrict__ thT, const ushort* __restrict__ phT,
    const ushort* __restrict__ g2s,
    float* __restrict__ y2part, int NCH)
{
    const int t = threadIdx.x;
    const int wave = t >> 6, lane = t & 63;
    const int q = lane >> 4, lm = lane & 15;
    const int b = blockIdx.y, ch = blockIdx.z;
    const int n0 = blockIdx.x * 64;
    const int n = n0 + wave * 16 + lm;
    const size_t bN = (size_t)b * NN;

    // S' B-frag (thT), invariant over m: B[k=c][j=n]
    const bf16x8 bT = *(const bf16x8*)(thT + (bN + n) * CI + 8 * q);

    f32x4 acc0 = {0.f, 0.f, 0.f, 0.f};
    f32x4 acc1 = {0.f, 0.f, 0.f, 0.f};
    const f32x4 z4 = {0.f, 0.f, 0.f, 0.f};

    const int mchunk = NN / NCH;
    const int mbeg = ch * mchunk, mend = mbeg + mchunk;
    const ushort* g2b = g2s + (size_t)b * CI * NN;

    for (int ms = mbeg; ms < mend; ms += 64) {
        const ushort* pa = phT + (bN + ms + lm) * CI + 8 * q;
        bf16x8 a0 = *(const bf16x8*)(pa);
        bf16x8 a1 = *(const bf16x8*)(pa + 16 * CI);
        bf16x8 a2 = *(const bf16x8*)(pa + 32 * CI);
        bf16x8 a3 = *(const bf16x8*)(pa + 48 * CI);
        f32x4 d0 = __builtin_amdgcn_mfma_f32_16x16x32_bf16(a0, bT, z4, 0, 0, 0);
        f32x4 d1 = __builtin_amdgcn_mfma_f32_16x16x32_bf16(a1, bT, z4, 0, 0, 0);
        f32x4 d2 = __builtin_amdgcn_mfma_f32_16x16x32_bf16(a2, bT, z4, 0, 0, 0);
        f32x4 d3 = __builtin_amdgcn_mfma_f32_16x16x32_bf16(a3, bT, z4, 0, 0, 0);

        f32x4 p0, p1, p2, p3;
#pragma unroll
        for (int r = 0; r < 4; r++) {
            p0[r] = __expf(d0[r]); p1[r] = __expf(d1[r]);
            p2[r] = __expf(d2[r]); p3[r] = __expf(d3[r]);
        }

        uint u00 = pk2(p0[0], p0[1]), u01 = pk2(p0[2], p0[3]);
        uint u10 = pk2(p1[0], p1[1]), u11 = pk2(p1[2], p1[3]);
        uint u20 = pk2(p2[0], p2[1]), u21 = pk2(p2[2], p2[3]);
        uint u30 = pk2(p3[0], p3[1]), u31 = pk2(p3[2], p3[3]);
        bf16x8 bP0 = mk8(u00, u01, u10, u11);
        bf16x8 bP1 = mk8(u20, u21, u30, u31);

        {
            const ushort* gp = g2b + (size_t)lm * NN + ms + 4 * q;
            uint2 lo = *(const uint2*)(gp);
            uint2 hi = *(const uint2*)(gp + 16);
            acc0 = __builtin_amdgcn_mfma_f32_16x16x32_bf16(mk8(lo.x, lo.y, hi.x, hi.y), bP0, acc0, 0, 0, 0);
            lo = *(const uint2*)(gp + 32);
            hi = *(const uint2*)(gp + 48);
            acc0 = __builtin_amdgcn_mfma_f32_16x16x32_bf16(mk8(lo.x, lo.y, hi.x, hi.y), bP1, acc0, 0, 0, 0);
        }
        {
            const ushort* gp = g2b + (size_t)(16 + lm) * NN + ms + 4 * q;
            uint2 lo = *(const uint2*)(gp);
            uint2 hi = *(const uint2*)(gp + 16);
            acc1 = __builtin_amdgcn_mfma_f32_16x16x32_bf16(mk8(lo.x, lo.y, hi.x, hi.y), bP0, acc1, 0, 0, 0);
            lo = *(const uint2*)(gp + 32);
            hi = *(const uint2*)(gp + 48);
            acc1 = __builtin_amdgcn_mfma_f32_16x16x32_bf16(mk8(lo.x, lo.y, hi.x, hi.y), bP1, acc1, 0, 0, 0);
        }
    }

    float* yp = y2part + (((size_t)ch * BB + b) * CI) * NN + n;
#pragma unroll
    for (int r = 0; r < 4; r++) {
        yp[(size_t)(4 * q + r) * NN] = acc0[r];
        yp[(size_t)(16 + 4 * q + r) * NN] = acc1[r];
    }
}

// ---------------------------------------------------------------------------
// final: reduce partials, normalize y1 by rZ, fused conv1x1+BN + residual.
// ---------------------------------------------------------------------------
__global__ __launch_bounds__(256) void final_kernel(
    const float* __restrict__ x1, const float* __restrict__ x2,
    const float* __restrict__ ww, const float* __restrict__ wb,
    const float* __restrict__ wga, const float* __restrict__ wbe,
    const float* __restrict__ wmu, const float* __restrict__ wva,
    const float* __restrict__ y1part, const float* __restrict__ y2part,
    const float* __restrict__ rZ, float* __restrict__ out, int NCH)
{
    int job = blockIdx.y;
    const float* part = job ? y2part : y1part;
    const float* x = job ? x2 : x1;
    float* o = out + (size_t)job * (BB * CC * NN);

    __shared__ __align__(16) float s_w[CC][CI];
    __shared__ float s_scale[CC], s_bias[CC];
    int t = threadIdx.x;
    if (t < CC) {
        float sc = wga[t] / sqrtf(wva[t] + EPS);
        s_scale[t] = sc;
        s_bias[t] = wbe[t] - wmu[t] * sc + wb[t] * sc;
    }
    __syncthreads();
    for (int i = t; i < CC * CI; i += 256) s_w[i / CI][i % CI] = ww[i] * s_scale[i / CI];
    __syncthreads();

    int idx = blockIdx.x * 256 + t;
    int b = idx >> 12, j = idx & (NN - 1);

    float y[CI];
#pragma unroll
    for (int c = 0; c < CI; c++) y[c] = 0.f;
    for (int ch = 0; ch < NCH; ch++) {
        const float* pp = part + (((size_t)ch * BB + b) * CI) * NN + j;
#pragma unroll
        for (int c = 0; c < CI; c++) y[c] += pp[(size_t)c * NN];
    }
    if (job == 0) {
        float r = rZ[idx];
#pragma unroll
        for (int c = 0; c < CI; c++) y[c] *= r;
    }

    const float* xp = x + ((size_t)b * CC) * NN + j;
    float* op = o + ((size_t)b * CC) * NN + j;
#pragma unroll
    for (int oo = 0; oo < CC; oo++) {
        float acc = s_bias[oo];
        const float4* wr = (const float4*)s_w[oo];
#pragma unroll
        for (int c4 = 0; c4 < CI / 4; c4++) {
            float4 wv = wr[c4];
            acc += wv.x * y[c4 * 4] + wv.y * y[c4 * 4 + 1] + wv.z * y[c4 * 4 + 2] + wv.w * y[c4 * 4 + 3];
        }
        op[(size_t)oo * NN] = xp[(size_t)oo * NN] + acc;
    }
}

// ---------------------------------------------------------------------------
extern "C" void kernel_launch(void* const* d_in, const int* in_sizes, int n_in,
                              void* d_out, int out_size, void* d_ws, size_t ws_size,
                              hipStream_t stream)
{
    const float* x1  = (const float*)d_in[0];
    const float* x2  = (const float*)d_in[1];
    const float* gw  = (const float*)d_in[2];
    const float* gb  = (const float*)d_in[3];
    const float* gga = (const float*)d_in[4];
    const float* gbe = (const float*)d_in[5];
    const float* gmu = (const float*)d_in[6];
    const float* gva = (const float*)d_in[7];
    const float* tw  = (const float*)d_in[8];
    const float* tb  = (const float*)d_in[9];
    const float* tga = (const float*)d_in[10];
    const float* tbe = (const float*)d_in[11];
    const float* tmu = (const float*)d_in[12];
    const float* tva = (const float*)d_in[13];
    const float* pw  = (const float*)d_in[14];
    const float* pb  = (const float*)d_in[15];
    const float* pga = (const float*)d_in[16];
    const float* pbe = (const float*)d_in[17];
    const float* pmu = (const float*)d_in[18];
    const float* pva = (const float*)d_in[19];
    const float* ww  = (const float*)d_in[20];
    const float* wb  = (const float*)d_in[21];
    const float* wga = (const float*)d_in[22];
    const float* wbe = (const float*)d_in[23];
    const float* wmu = (const float*)d_in[24];
    const float* wva = (const float*)d_in[25];

    int NC = 4;
    while (NC > 1) {
        size_t need = 5ull * PROJ_SZ * 2                 // bf16 proj buffers
                    + (size_t)NC * BB * NN * 4           // zpart
                    + (size_t)BB * NN * 4                // rZ
                    + 2ull * NC * BB * CI * NN * 4;      // y1p + y2p
        if (need <= ws_size) break;
        NC >>= 1;
    }

    ushort* g1   = (ushort*)d_ws;
    ushort* g2   = g1 + PROJ_SZ;
    ushort* g2s  = g2 + PROJ_SZ;
    ushort* thT  = g2s + PROJ_SZ;
    ushort* phT  = thT + PROJ_SZ;
    float* zpart = (float*)(phT + PROJ_SZ);
    float* rZ    = zpart + (size_t)NC * BB * NN;
    float* y1p   = rZ + (size_t)BB * NN;
    float* y2p   = y1p + (size_t)NC * BB * CI * NN;

    proj_kernel<<<dim3(BB * NN / 256, 4), 256, 0, stream>>>(
        x1, x2, gw, gb, gga, gbe, gmu, gva, tw, tb, tga, tbe, tmu, tva,
        pw, pb, pga, pbe, pmu, pva, g1, g2, thT, phT);

    passA_kernel<<<dim3(NN / 64, BB, NC), 256, 0, stream>>>(
        thT, phT, g1, zpart, y1p, NC);

    combine_kernel<<<dim3(BB * NN / 256), 256, 0, stream>>>(
        zpart, g2, rZ, g2s, NC);

    passB_kernel<<<dim3(NN / 64, BB, NC), 256, 0, stream>>>(
        thT, phT, g2s, y2p, NC);

    final_kernel<<<dim3(BB * NN / 256, 2), 256, 0, stream>>>(
        x1, x2, ww, wb, wga, wbe, wmu, wva, y1p, y2p, rZ, (float*)d_out, NC);
}

// Round 9
// 249.139 us; speedup vs baseline: 1.2753x; 1.2753x over previous
//
#include <hip/hip_runtime.h>
#include <math.h>

#define BB 4
#define CC 64
#define CI 32
#define NN 4096
#define EPS 1e-5f

#define PROJ_SZ (BB * CI * NN) /* 524288 elems */

typedef __attribute__((ext_vector_type(8))) short bf16x8;
typedef __attribute__((ext_vector_type(4))) float f32x4;

// f32 -> bf16 with round-to-nearest-even (raw-bit math; finite inputs only)
__device__ __forceinline__ ushort f2bf(float f) {
    uint u = __builtin_bit_cast(uint, f);
    u += 0x7FFFu + ((u >> 16) & 1u);
    return (ushort)(u >> 16);
}
__device__ __forceinline__ float bf2f(ushort h) {
    uint u = (uint)h << 16;
    return __builtin_bit_cast(float, u);
}
// packed {bf16(a), bf16(b)} via the HW instruction (no builtin on gfx950)
__device__ __forceinline__ uint pk2(float a, float b) {
    uint r;
    asm("v_cvt_pk_bf16_f32 %0, %1, %2" : "=v"(r) : "v"(a), "v"(b));
    return r;
}
__device__ __forceinline__ bf16x8 mk8(uint a, uint b, uint c, uint d) {
    uint4 u; u.x = a; u.y = b; u.z = c; u.w = d;
    return __builtin_bit_cast(bf16x8, u);
}
// pi permutation: k-slot -> n offset within 32-block (see passA packing)
// pi(8q+e) = 4q + (e&3) + 16*(e>>2)
// inv:  pos(r) = 8*((r&15)>>2) + (r&3) + 4*(r>>4)
__device__ __forceinline__ int inv_pi(int r) {
    return 8 * ((r & 15) >> 2) + (r & 3) + 4 * (r >> 4);
}

// ---------------------------------------------------------------------------
// proj: BN -> 1x1 conv, emits bf16.
// job 0: g(x1)->g1p  pi-packed [b][nb(128)][c(32)][pos(32)]
// job 1: g(x2)->g2   [b][c][n]
// job 2: th(x1)->thT [b][n][CI]  (scaled by log2(e) so exp(S)=exp2(S'))
// job 3: ph(x2)->phT [b][m][CI]
// ---------------------------------------------------------------------------
__global__ __launch_bounds__(256) void proj_kernel(
    const float* __restrict__ x1, const float* __restrict__ x2,
    const float* __restrict__ gw, const float* __restrict__ gb,
    const float* __restrict__ gga, const float* __restrict__ gbe,
    const float* __restrict__ gmu, const float* __restrict__ gva,
    const float* __restrict__ tw, const float* __restrict__ tb,
    const float* __restrict__ tga, const float* __restrict__ tbe,
    const float* __restrict__ tmu, const float* __restrict__ tva,
    const float* __restrict__ pw, const float* __restrict__ pb,
    const float* __restrict__ pga, const float* __restrict__ pbe,
    const float* __restrict__ pmu, const float* __restrict__ pva,
    ushort* __restrict__ g1p, ushort* __restrict__ g2o,
    ushort* __restrict__ thTo, ushort* __restrict__ phTo)
{
    int job = blockIdx.y;
    const float* src = (job == 0 || job == 2) ? x1 : x2;
    const float *w, *bia, *ga, *be, *mu, *va;
    if (job <= 1)      { w = gw; bia = gb; ga = gga; be = gbe; mu = gmu; va = gva; }
    else if (job == 2) { w = tw; bia = tb; ga = tga; be = tbe; mu = tmu; va = tva; }
    else               { w = pw; bia = pb; ga = pga; be = pbe; mu = pmu; va = pva; }

    __shared__ __align__(16) float s_w[CI][CC];
    __shared__ float s_scale[CC], s_shift[CC], s_b[CI];
    int t = threadIdx.x;
    if (t < CC) {
        float sc = ga[t] / sqrtf(va[t] + EPS);
        s_scale[t] = sc;
        s_shift[t] = be[t] - mu[t] * sc;
    }
    if (t >= CC && t < CC + CI) s_b[t - CC] = bia[t - CC];
    for (int i = t; i < CI * CC; i += 256) s_w[i / CC][i % CC] = w[i];
    __syncthreads();

    int bn = blockIdx.x * 256 + t;
    int b = bn >> 12, n = bn & (NN - 1);
    const float* xp = src + ((size_t)b * CC) * NN + n;

    float acc[CI];
#pragma unroll
    for (int o = 0; o < CI; o++) acc[o] = s_b[o];

#pragma unroll 4
    for (int c4 = 0; c4 < CC / 4; c4++) {
        float xv0 = xp[(size_t)(c4 * 4 + 0) * NN] * s_scale[c4 * 4 + 0] + s_shift[c4 * 4 + 0];
        float xv1 = xp[(size_t)(c4 * 4 + 1) * NN] * s_scale[c4 * 4 + 1] + s_shift[c4 * 4 + 1];
        float xv2 = xp[(size_t)(c4 * 4 + 2) * NN] * s_scale[c4 * 4 + 2] + s_shift[c4 * 4 + 2];
        float xv3 = xp[(size_t)(c4 * 4 + 3) * NN] * s_scale[c4 * 4 + 3] + s_shift[c4 * 4 + 3];
#pragma unroll
        for (int o = 0; o < CI; o++) {
            float4 wv = *(const float4*)&s_w[o][c4 * 4];
            acc[o] += wv.x * xv0 + wv.y * xv1 + wv.z * xv2 + wv.w * xv3;
        }
    }

    if (job == 0) {
        // pi-packed: g1p[((b*128 + nb)*32 + c)*32 + pos], pos = inv_pi(n&31)
        int nb = n >> 5, pos = inv_pi(n & 31);
        ushort* dp = g1p + (((size_t)b * 128 + nb) * 32) * 32 + pos;
#pragma unroll
        for (int o = 0; o < CI; o++) dp[o * 32] = f2bf(acc[o]);
    } else if (job == 1) {
        ushort* dp = g2o + ((size_t)b * CI) * NN + n;
#pragma unroll
        for (int o = 0; o < CI; o++) dp[(size_t)o * NN] = f2bf(acc[o]);
    } else {
        if (job == 2) {
#pragma unroll
            for (int o = 0; o < CI; o++) acc[o] *= 1.44269504f;  // log2(e)
        }
        uint u[16];
#pragma unroll
        for (int i = 0; i < 16; i++)
            u[i] = (uint)f2bf(acc[2 * i]) | ((uint)f2bf(acc[2 * i + 1]) << 16);
        uint4* dp = (uint4*)((job == 2 ? thTo : phTo) + ((size_t)b * NN + n) * CI);
#pragma unroll
        for (int i = 0; i < 4; i++) {
            uint4 v; v.x = u[4 * i]; v.y = u[4 * i + 1]; v.z = u[4 * i + 2]; v.w = u[4 * i + 3];
            dp[i] = v;
        }
    }
}

// ---------------------------------------------------------------------------
// passA: block owns 64-m tile (wave w -> m-subtile w), streams an n-chunk.
// S[n,m] via mfma 16x16x32 (A=thT rows n, B=phT cols m). P=exp2(S) in D-frags;
// PV uses pi-permuted k-order so B-operand is the lane's own packed P values
// and the A-operand (g1p) is a single coalesced 16B load per frag.
// ---------------------------------------------------------------------------
__global__ __launch_bounds__(256, 8) void passA_kernel(
    const ushort* __restrict__ thT, const ushort* __restrict__ phT,
    const ushort* __restrict__ g1p,
    float* __restrict__ zpart, float* __restrict__ y1part, int NCH)
{
    const int t = threadIdx.x;
    const int wave = t >> 6, lane = t & 63;
    const int q = lane >> 4, lm = lane & 15;
    const int b = blockIdx.y, ch = blockIdx.z;
    const int m0 = blockIdx.x * 64;
    const int m = m0 + wave * 16 + lm;
    const size_t bN = (size_t)b * NN;

    // S B-frag (phT), invariant over n: B[k=c][j=m]
    const bf16x8 bS = *(const bf16x8*)(phT + (bN + m) * CI + 8 * q);

    f32x4 acc0 = {0.f, 0.f, 0.f, 0.f};
    f32x4 acc1 = {0.f, 0.f, 0.f, 0.f};
    const f32x4 z4 = {0.f, 0.f, 0.f, 0.f};
    float zacc = 0.f;

    const int nchunk = NN / NCH;
    const int nbeg = ch * nchunk;
    // thT A-frag base: row n = ns+lm, k-slice 8q
    const ushort* ta = thT + (bN + nbeg + lm) * CI + 8 * q;
    // g1p base for this lane: plane (b, nb = nbeg/32), row c=lm, pos 8q
    const ushort* gp = g1p + (((size_t)b * 128 + (nbeg >> 5)) * 32 + lm) * 32 + 8 * q;

    for (int it = 0; it < nchunk / 64; it++) {
        // A-frags for S (4 x 16B, offsets fold to 0/1024/2048/3072 bytes)
        bf16x8 a0 = *(const bf16x8*)(ta);
        bf16x8 a1 = *(const bf16x8*)(ta + 16 * CI);
        bf16x8 a2 = *(const bf16x8*)(ta + 32 * CI);
        bf16x8 a3 = *(const bf16x8*)(ta + 48 * CI);
        // A-frags for PV (4 x 16B, offsets 0/1024/2048/3072 bytes)
        bf16x8 ga00 = *(const bf16x8*)(gp);           // c=lm,    n-block 0
        bf16x8 ga10 = *(const bf16x8*)(gp + 512);     // c=16+lm, n-block 0
        bf16x8 ga01 = *(const bf16x8*)(gp + 1024);    // c=lm,    n-block 1
        bf16x8 ga11 = *(const bf16x8*)(gp + 1536);    // c=16+lm, n-block 1

        f32x4 d0 = __builtin_amdgcn_mfma_f32_16x16x32_bf16(a0, bS, z4, 0, 0, 0);
        f32x4 d1 = __builtin_amdgcn_mfma_f32_16x16x32_bf16(a1, bS, z4, 0, 0, 0);
        f32x4 d2 = __builtin_amdgcn_mfma_f32_16x16x32_bf16(a2, bS, z4, 0, 0, 0);
        f32x4 d3 = __builtin_amdgcn_mfma_f32_16x16x32_bf16(a3, bS, z4, 0, 0, 0);

        f32x4 p0, p1, p2, p3;
#pragma unroll
        for (int r = 0; r < 4; r++) {
            p0[r] = __builtin_amdgcn_exp2f(d0[r]);
            p1[r] = __builtin_amdgcn_exp2f(d1[r]);
            p2[r] = __builtin_amdgcn_exp2f(d2[r]);
            p3[r] = __builtin_amdgcn_exp2f(d3[r]);
        }
        zacc += ((p0[0] + p0[1]) + (p0[2] + p0[3]))
              + ((p1[0] + p1[1]) + (p1[2] + p1[3]))
              + ((p2[0] + p2[1]) + (p2[2] + p2[3]))
              + ((p3[0] + p3[1]) + (p3[2] + p3[3]));

        bf16x8 bP0 = mk8(pk2(p0[0], p0[1]), pk2(p0[2], p0[3]),
                         pk2(p1[0], p1[1]), pk2(p1[2], p1[3]));
        bf16x8 bP1 = mk8(pk2(p2[0], p2[1]), pk2(p2[2], p2[3]),
                         pk2(p3[0], p3[1]), pk2(p3[2], p3[3]));

        acc0 = __builtin_amdgcn_mfma_f32_16x16x32_bf16(ga00, bP0, acc0, 0, 0, 0);
        acc0 = __builtin_amdgcn_mfma_f32_16x16x32_bf16(ga01, bP1, acc0, 0, 0, 0);
        acc1 = __builtin_amdgcn_mfma_f32_16x16x32_bf16(ga10, bP0, acc1, 0, 0, 0);
        acc1 = __builtin_amdgcn_mfma_f32_16x16x32_bf16(ga11, bP1, acc1, 0, 0, 0);

        ta += 64 * CI;
        gp += 2048;
    }

    // z[m]: lanes q=0..3 share the same m
    zacc += __shfl_xor(zacc, 16);
    zacc += __shfl_xor(zacc, 32);
    if (q == 0) zpart[((size_t)ch * BB + b) * NN + m] = zacc;

    float* yp = y1part + (((size_t)ch * BB + b) * CI) * NN + m;
#pragma unroll
    for (int r = 0; r < 4; r++) {
        yp[(size_t)(4 * q + r) * NN] = acc0[r];
        yp[(size_t)(16 + 4 * q + r) * NN] = acc1[r];
    }
}

// ---------------------------------------------------------------------------
// combine: rZ = 1/sum_ch z ; g2s = pi-packed bf16(g2[c][m] * rZ[m])
// ---------------------------------------------------------------------------
__global__ __launch_bounds__(256) void combine_kernel(
    const float* __restrict__ zpart, const ushort* __restrict__ g2,
    float* __restrict__ rZ, ushort* __restrict__ g2s, int NCH)
{
    int idx = blockIdx.x * 256 + threadIdx.x;   // b*NN + m
    float z = 0.f;
    for (int ch = 0; ch < NCH; ch++) z += zpart[(size_t)ch * BB * NN + idx];
    float r = 1.f / z;
    rZ[idx] = r;
    int b = idx >> 12, mm = idx & (NN - 1);
    int mb = mm >> 5, pos = inv_pi(mm & 31);
    const ushort* gpi = g2 + (size_t)b * CI * NN + mm;
    ushort* gso = g2s + (((size_t)b * 128 + mb) * 32) * 32 + pos;
#pragma unroll
    for (int c = 0; c < CI; c++) gso[c * 32] = f2bf(bf2f(gpi[(size_t)c * NN]) * r);
}

// ---------------------------------------------------------------------------
// passB: block owns 64-n tile, streams an m-chunk.
// S'[m,n] via mfma (A=phT rows m, B=thT cols n); y2 += g2s x P' (pi k-order).
// ---------------------------------------------------------------------------
__global__ __launch_bounds__(256, 8) void passB_kernel(
    const ushort* __restrict__ thT, const ushort* __restrict__ phT,
    const ushort* __restrict__ g2s,
    float* __restrict__ y2part, int NCH)
{
    const int t = threadIdx.x;
    const int wave = t >> 6, lane = t & 63;
    const int q = lane >> 4, lm = lane & 15;
    const int b = blockIdx.y, ch = blockIdx.z;
    const int n0 = blockIdx.x * 64;
    const int n = n0 + wave * 16 + lm;
    const size_t bN = (size_t)b * NN;

    const bf16x8 bT = *(const bf16x8*)(thT + (bN + n) * CI + 8 * q);

    f32x4 acc0 = {0.f, 0.f, 0.f, 0.f};
    f32x4 acc1 = {0.f, 0.f, 0.f, 0.f};
    const f32x4 z4 = {0.f, 0.f, 0.f, 0.f};

    const int mchunk = NN / NCH;
    const int mbeg = ch * mchunk;
    const ushort* pa = phT + (bN + mbeg + lm) * CI + 8 * q;
    const ushort* gp = g2s + (((size_t)b * 128 + (mbeg >> 5)) * 32 + lm) * 32 + 8 * q;

    for (int it = 0; it < mchunk / 64; it++) {
        bf16x8 a0 = *(const bf16x8*)(pa);
        bf16x8 a1 = *(const bf16x8*)(pa + 16 * CI);
        bf16x8 a2 = *(const bf16x8*)(pa + 32 * CI);
        bf16x8 a3 = *(const bf16x8*)(pa + 48 * CI);
        bf16x8 ga00 = *(const bf16x8*)(gp);
        bf16x8 ga10 = *(const bf16x8*)(gp + 512);
        bf16x8 ga01 = *(const bf16x8*)(gp + 1024);
        bf16x8 ga11 = *(const bf16x8*)(gp + 1536);

        f32x4 d0 = __builtin_amdgcn_mfma_f32_16x16x32_bf16(a0, bT, z4, 0, 0, 0);
        f32x4 d1 = __builtin_amdgcn_mfma_f32_16x16x32_bf16(a1, bT, z4, 0, 0, 0);
        f32x4 d2 = __builtin_amdgcn_mfma_f32_16x16x32_bf16(a2, bT, z4, 0, 0, 0);
        f32x4 d3 = __builtin_amdgcn_mfma_f32_16x16x32_bf16(a3, bT, z4, 0, 0, 0);

        f32x4 p0, p1, p2, p3;
#pragma unroll
        for (int r = 0; r < 4; r++) {
            p0[r] = __builtin_amdgcn_exp2f(d0[r]);
            p1[r] = __builtin_amdgcn_exp2f(d1[r]);
            p2[r] = __builtin_amdgcn_exp2f(d2[r]);
            p3[r] = __builtin_amdgcn_exp2f(d3[r]);
        }

        bf16x8 bP0 = mk8(pk2(p0[0], p0[1]), pk2(p0[2], p0[3]),
                         pk2(p1[0], p1[1]), pk2(p1[2], p1[3]));
        bf16x8 bP1 = mk8(pk2(p2[0], p2[1]), pk2(p2[2], p2[3]),
                         pk2(p3[0], p3[1]), pk2(p3[2], p3[3]));

        acc0 = __builtin_amdgcn_mfma_f32_16x16x32_bf16(ga00, bP0, acc0, 0, 0, 0);
        acc0 = __builtin_amdgcn_mfma_f32_16x16x32_bf16(ga01, bP1, acc0, 0, 0, 0);
        acc1 = __builtin_amdgcn_mfma_f32_16x16x32_bf16(ga10, bP0, acc1, 0, 0, 0);
        acc1 = __builtin_amdgcn_mfma_f32_16x16x32_bf16(ga11, bP1, acc1, 0, 0, 0);

        pa += 64 * CI;
        gp += 2048;
    }

    float* yp = y2part + (((size_t)ch * BB + b) * CI) * NN + n;
#pragma unroll
    for (int r = 0; r < 4; r++) {
        yp[(size_t)(4 * q + r) * NN] = acc0[r];
        yp[(size_t)(16 + 4 * q + r) * NN] = acc1[r];
    }
}

// ---------------------------------------------------------------------------
// final: reduce partials, normalize y1 by rZ, fused conv1x1+BN + residual.
// ---------------------------------------------------------------------------
__global__ __launch_bounds__(256) void final_kernel(
    const float* __restrict__ x1, const float* __restrict__ x2,
    const float* __restrict__ ww, const float* __restrict__ wb,
    const float* __restrict__ wga, const float* __restrict__ wbe,
    const float* __restrict__ wmu, const float* __restrict__ wva,
    const float* __restrict__ y1part, const float* __restrict__ y2part,
    const float* __restrict__ rZ, float* __restrict__ out, int NCH)
{
    int job = blockIdx.y;
    const float* part = job ? y2part : y1part;
    const float* x = job ? x2 : x1;
    float* o = out + (size_t)job * (BB * CC * NN);

    __shared__ __align__(16) float s_w[CC][CI];
    __shared__ float s_scale[CC], s_bias[CC];
    int t = threadIdx.x;
    if (t < CC) {
        float sc = wga[t] / sqrtf(wva[t] + EPS);
        s_scale[t] = sc;
        s_bias[t] = wbe[t] - wmu[t] * sc + wb[t] * sc;
    }
    __syncthreads();
    for (int i = t; i < CC * CI; i += 256) s_w[i / CI][i % CI] = ww[i] * s_scale[i / CI];
    __syncthreads();

    int idx = blockIdx.x * 256 + t;
    int b = idx >> 12, j = idx & (NN - 1);

    float y[CI];
#pragma unroll
    for (int c = 0; c < CI; c++) y[c] = 0.f;
    for (int ch = 0; ch < NCH; ch++) {
        const float* pp = part + (((size_t)ch * BB + b) * CI) * NN + j;
#pragma unroll
        for (int c = 0; c < CI; c++) y[c] += pp[(size_t)c * NN];
    }
    if (job == 0) {
        float r = rZ[idx];
#pragma unroll
        for (int c = 0; c < CI; c++) y[c] *= r;
    }

    const float* xp = x + ((size_t)b * CC) * NN + j;
    float* op = o + ((size_t)b * CC) * NN + j;
#pragma unroll
    for (int oo = 0; oo < CC; oo++) {
        float acc = s_bias[oo];
        const float4* wr = (const float4*)s_w[oo];
#pragma unroll
        for (int c4 = 0; c4 < CI / 4; c4++) {
            float4 wv = wr[c4];
            acc += wv.x * y[c4 * 4] + wv.y * y[c4 * 4 + 1] + wv.z * y[c4 * 4 + 2] + wv.w * y[c4 * 4 + 3];
        }
        op[(size_t)oo * NN] = xp[(size_t)oo * NN] + acc;
    }
}

// ---------------------------------------------------------------------------
extern "C" void kernel_launch(void* const* d_in, const int* in_sizes, int n_in,
                              void* d_out, int out_size, void* d_ws, size_t ws_size,
                              hipStream_t stream)
{
    const float* x1  = (const float*)d_in[0];
    const float* x2  = (const float*)d_in[1];
    const float* gw  = (const float*)d_in[2];
    const float* gb  = (const float*)d_in[3];
    const float* gga = (const float*)d_in[4];
    const float* gbe = (const float*)d_in[5];
    const float* gmu = (const float*)d_in[6];
    const float* gva = (const float*)d_in[7];
    const float* tw  = (const float*)d_in[8];
    const float* tb  = (const float*)d_in[9];
    const float* tga = (const float*)d_in[10];
    const float* tbe = (const float*)d_in[11];
    const float* tmu = (const float*)d_in[12];
    const float* tva = (const float*)d_in[13];
    const float* pw  = (const float*)d_in[14];
    const float* pb  = (const float*)d_in[15];
    const float* pga = (const float*)d_in[16];
    const float* pbe = (const float*)d_in[17];
    const float* pmu = (const float*)d_in[18];
    const float* pva = (const float*)d_in[19];
    const float* ww  = (const float*)d_in[20];
    const float* wb  = (const float*)d_in[21];
    const float* wga = (const float*)d_in[22];
    const float* wbe = (const float*)d_in[23];
    const float* wmu = (const float*)d_in[24];
    const float* wva = (const float*)d_in[25];

    int NC = 8;
    while (NC > 1) {
        size_t need = 5ull * PROJ_SZ * 2                 // bf16 proj buffers
                    + (size_t)NC * BB * NN * 4           // zpart
                    + (size_t)BB * NN * 4                // rZ
                    + 2ull * NC * BB * CI * NN * 4;      // y1p + y2p
        if (need <= ws_size) break;
        NC >>= 1;
    }

    ushort* g1p  = (ushort*)d_ws;
    ushort* g2   = g1p + PROJ_SZ;
    ushort* g2s  = g2 + PROJ_SZ;
    ushort* thT  = g2s + PROJ_SZ;
    ushort* phT  = thT + PROJ_SZ;
    float* zpart = (float*)(phT + PROJ_SZ);
    float* rZ    = zpart + (size_t)NC * BB * NN;
    float* y1p   = rZ + (size_t)BB * NN;
    float* y2p   = y1p + (size_t)NC * BB * CI * NN;

    proj_kernel<<<dim3(BB * NN / 256, 4), 256, 0, stream>>>(
        x1, x2, gw, gb, gga, gbe, gmu, gva, tw, tb, tga, tbe, tmu, tva,
        pw, pb, pga, pbe, pmu, pva, g1p, g2, thT, phT);

    passA_kernel<<<dim3(NN / 64, BB, NC), 256, 0, stream>>>(
        thT, phT, g1p, zpart, y1p, NC);

    combine_kernel<<<dim3(BB * NN / 256), 256, 0, stream>>>(
        zpart, g2, rZ, g2s, NC);

    passB_kernel<<<dim3(NN / 64, BB, NC), 256, 0, stream>>>(
        thT, phT, g2s, y2p, NC);

    final_kernel<<<dim3(BB * NN / 256, 2), 256, 0, stream>>>(
        x1, x2, ww, wb, wga, wbe, wmu, wva, y1p, y2p, rZ, (float*)d_out, NC);
}

// Round 11
// 218.747 us; speedup vs baseline: 1.4525x; 1.1389x over previous
//
#include <hip/hip_runtime.h>
#include <math.h>

#define BB 4
#define CC 64
#define CI 32
#define NN 4096
#define EPS 1e-5f

#define PROJ_SZ (BB * CI * NN) /* 524288 elems */

typedef __attribute__((ext_vector_type(8))) short bf16x8;
typedef __attribute__((ext_vector_type(4))) float f32x4;

// f32 -> bf16 with round-to-nearest-even (raw-bit math; finite inputs only)
__device__ __forceinline__ ushort f2bf(float f) {
    uint u = __builtin_bit_cast(uint, f);
    u += 0x7FFFu + ((u >> 16) & 1u);
    return (ushort)(u >> 16);
}
__device__ __forceinline__ float bf2f(ushort h) {
    uint u = (uint)h << 16;
    return __builtin_bit_cast(float, u);
}
// packed {bf16(a), bf16(b)} via the HW instruction (no builtin on gfx950)
__device__ __forceinline__ uint pk2(float a, float b) {
    uint r;
    asm("v_cvt_pk_bf16_f32 %0, %1, %2" : "=v"(r) : "v"(a), "v"(b));
    return r;
}
__device__ __forceinline__ bf16x8 mk8(uint a, uint b, uint c, uint d) {
    uint4 u; u.x = a; u.y = b; u.z = c; u.w = d;
    return __builtin_bit_cast(bf16x8, u);
}
// pi permutation: k-slot -> n offset within 32-block (see passA packing)
// pi(8q+e) = 4q + (e&3) + 16*(e>>2)
// inv:  pos(r) = 8*((r&15)>>2) + (r&3) + 4*(r>>4)
__device__ __forceinline__ int inv_pi(int r) {
    return 8 * ((r & 15) >> 2) + (r & 3) + 4 * (r >> 4);
}

// ---------------------------------------------------------------------------
// proj: BN -> 1x1 conv, emits bf16.
// job 0: g(x1)->g1p  pi-packed [b][nb(128)][c(32)][pos(32)]
// job 1: g(x2)->g2   [b][c][n]
// job 2: th(x1)->thT [b][n][CI]  (scaled by log2(e) so exp(S)=exp2(S'))
// job 3: ph(x2)->phT [b][m][CI]
// ---------------------------------------------------------------------------
__global__ __launch_bounds__(256) void proj_kernel(
    const float* __restrict__ x1, const float* __restrict__ x2,
    const float* __restrict__ gw, const float* __restrict__ gb,
    const float* __restrict__ gga, const float* __restrict__ gbe,
    const float* __restrict__ gmu, const float* __restrict__ gva,
    const float* __restrict__ tw, const float* __restrict__ tb,
    const float* __restrict__ tga, const float* __restrict__ tbe,
    const float* __restrict__ tmu, const float* __restrict__ tva,
    const float* __restrict__ pw, const float* __restrict__ pb,
    const float* __restrict__ pga, const float* __restrict__ pbe,
    const float* __restrict__ pmu, const float* __restrict__ pva,
    ushort* __restrict__ g1p, ushort* __restrict__ g2o,
    ushort* __restrict__ thTo, ushort* __restrict__ phTo)
{
    int job = blockIdx.y;
    const float* src = (job == 0 || job == 2) ? x1 : x2;
    const float *w, *bia, *ga, *be, *mu, *va;
    if (job <= 1)      { w = gw; bia = gb; ga = gga; be = gbe; mu = gmu; va = gva; }
    else if (job == 2) { w = tw; bia = tb; ga = tga; be = tbe; mu = tmu; va = tva; }
    else               { w = pw; bia = pb; ga = pga; be = pbe; mu = pmu; va = pva; }

    __shared__ __align__(16) float s_w[CI][CC];
    __shared__ float s_scale[CC], s_shift[CC], s_b[CI];
    int t = threadIdx.x;
    if (t < CC) {
        float sc = ga[t] / sqrtf(va[t] + EPS);
        s_scale[t] = sc;
        s_shift[t] = be[t] - mu[t] * sc;
    }
    if (t >= CC && t < CC + CI) s_b[t - CC] = bia[t - CC];
    for (int i = t; i < CI * CC; i += 256) s_w[i / CC][i % CC] = w[i];
    __syncthreads();

    int bn = blockIdx.x * 256 + t;
    int b = bn >> 12, n = bn & (NN - 1);
    const float* xp = src + ((size_t)b * CC) * NN + n;

    float acc[CI];
#pragma unroll
    for (int o = 0; o < CI; o++) acc[o] = s_b[o];

#pragma unroll 4
    for (int c4 = 0; c4 < CC / 4; c4++) {
        float xv0 = xp[(size_t)(c4 * 4 + 0) * NN] * s_scale[c4 * 4 + 0] + s_shift[c4 * 4 + 0];
        float xv1 = xp[(size_t)(c4 * 4 + 1) * NN] * s_scale[c4 * 4 + 1] + s_shift[c4 * 4 + 1];
        float xv2 = xp[(size_t)(c4 * 4 + 2) * NN] * s_scale[c4 * 4 + 2] + s_shift[c4 * 4 + 2];
        float xv3 = xp[(size_t)(c4 * 4 + 3) * NN] * s_scale[c4 * 4 + 3] + s_shift[c4 * 4 + 3];
#pragma unroll
        for (int o = 0; o < CI; o++) {
            float4 wv = *(const float4*)&s_w[o][c4 * 4];
            acc[o] += wv.x * xv0 + wv.y * xv1 + wv.z * xv2 + wv.w * xv3;
        }
    }

    if (job == 0) {
        // pi-packed: g1p[((b*128 + nb)*32 + c)*32 + pos], pos = inv_pi(n&31)
        int nb = n >> 5, pos = inv_pi(n & 31);
        ushort* dp = g1p + (((size_t)b * 128 + nb) * 32) * 32 + pos;
#pragma unroll
        for (int o = 0; o < CI; o++) dp[o * 32] = f2bf(acc[o]);
    } else if (job == 1) {
        ushort* dp = g2o + ((size_t)b * CI) * NN + n;
#pragma unroll
        for (int o = 0; o < CI; o++) dp[(size_t)o * NN] = f2bf(acc[o]);
    } else {
        if (job == 2) {
#pragma unroll
            for (int o = 0; o < CI; o++) acc[o] *= 1.44269504f;  // log2(e)
        }
        uint u[16];
#pragma unroll
        for (int i = 0; i < 16; i++)
            u[i] = (uint)f2bf(acc[2 * i]) | ((uint)f2bf(acc[2 * i + 1]) << 16);
        uint4* dp = (uint4*)((job == 2 ? thTo : phTo) + ((size_t)b * NN + n) * CI);
#pragma unroll
        for (int i = 0; i < 4; i++) {
            uint4 v; v.x = u[4 * i]; v.y = u[4 * i + 1]; v.z = u[4 * i + 2]; v.w = u[4 * i + 3];
            dp[i] = v;
        }
    }
}

// ---------------------------------------------------------------------------
// passA: block owns 64-m tile (wave w -> m-subtile w), streams an n-chunk.
// S[n,m] via mfma 16x16x32 (A=thT rows n, B=phT cols m). P=exp2(S) in D-frags;
// PV uses pi-permuted k-order so B-operand is the lane's own packed P values
// and the A-operand (g1p) is a single coalesced 16B load per frag.
// ---------------------------------------------------------------------------
__global__ __launch_bounds__(256, 8) void passA_kernel(
    const ushort* __restrict__ thT, const ushort* __restrict__ phT,
    const ushort* __restrict__ g1p,
    float* __restrict__ zpart, float* __restrict__ y1part, int NCH)
{
    const int t = threadIdx.x;
    const int wave = t >> 6, lane = t & 63;
    const int q = lane >> 4, lm = lane & 15;
    const int b = blockIdx.y, ch = blockIdx.z;
    const int m0 = blockIdx.x * 64;
    const int m = m0 + wave * 16 + lm;
    const size_t bN = (size_t)b * NN;

    // S B-frag (phT), invariant over n: B[k=c][j=m]
    const bf16x8 bS = *(const bf16x8*)(phT + (bN + m) * CI + 8 * q);

    f32x4 acc0 = {0.f, 0.f, 0.f, 0.f};
    f32x4 acc1 = {0.f, 0.f, 0.f, 0.f};
    const f32x4 z4 = {0.f, 0.f, 0.f, 0.f};
    float zacc = 0.f;

    const int nchunk = NN / NCH;
    const int nbeg = ch * nchunk;
    // thT A-frag base: row n = ns+lm, k-slice 8q
    const ushort* ta = thT + (bN + nbeg + lm) * CI + 8 * q;
    // g1p base for this lane: plane (b, nb = nbeg/32), row c=lm, pos 8q
    const ushort* gp = g1p + (((size_t)b * 128 + (nbeg >> 5)) * 32 + lm) * 32 + 8 * q;

    for (int it = 0; it < nchunk / 64; it++) {
        // A-frags for S (4 x 16B, offsets fold to 0/1024/2048/3072 bytes)
        bf16x8 a0 = *(const bf16x8*)(ta);
        bf16x8 a1 = *(const bf16x8*)(ta + 16 * CI);
        bf16x8 a2 = *(const bf16x8*)(ta + 32 * CI);
        bf16x8 a3 = *(const bf16x8*)(ta + 48 * CI);
        // A-frags for PV (4 x 16B, offsets 0/1024/2048/3072 bytes)
        bf16x8 ga00 = *(const bf16x8*)(gp);           // c=lm,    n-block 0
        bf16x8 ga10 = *(const bf16x8*)(gp + 512);     // c=16+lm, n-block 0
        bf16x8 ga01 = *(const bf16x8*)(gp + 1024);    // c=lm,    n-block 1
        bf16x8 ga11 = *(const bf16x8*)(gp + 1536);    // c=16+lm, n-block 1

        f32x4 d0 = __builtin_amdgcn_mfma_f32_16x16x32_bf16(a0, bS, z4, 0, 0, 0);
        f32x4 d1 = __builtin_amdgcn_mfma_f32_16x16x32_bf16(a1, bS, z4, 0, 0, 0);
        f32x4 d2 = __builtin_amdgcn_mfma_f32_16x16x32_bf16(a2, bS, z4, 0, 0, 0);
        f32x4 d3 = __builtin_amdgcn_mfma_f32_16x16x32_bf16(a3, bS, z4, 0, 0, 0);

        f32x4 p0, p1, p2, p3;
#pragma unroll
        for (int r = 0; r < 4; r++) {
            p0[r] = __builtin_amdgcn_exp2f(d0[r]);
            p1[r] = __builtin_amdgcn_exp2f(d1[r]);
            p2[r] = __builtin_amdgcn_exp2f(d2[r]);
            p3[r] = __builtin_amdgcn_exp2f(d3[r]);
        }
        zacc += ((p0[0] + p0[1]) + (p0[2] + p0[3]))
              + ((p1[0] + p1[1]) + (p1[2] + p1[3]))
              + ((p2[0] + p2[1]) + (p2[2] + p2[3]))
              + ((p3[0] + p3[1]) + (p3[2] + p3[3]));

        bf16x8 bP0 = mk8(pk2(p0[0], p0[1]), pk2(p0[2], p0[3]),
                         pk2(p1[0], p1[1]), pk2(p1[2], p1[3]));
        bf16x8 bP1 = mk8(pk2(p2[0], p2[1]), pk2(p2[2], p2[3]),
                         pk2(p3[0], p3[1]), pk2(p3[2], p3[3]));

        acc0 = __builtin_amdgcn_mfma_f32_16x16x32_bf16(ga00, bP0, acc0, 0, 0, 0);
        acc0 = __builtin_amdgcn_mfma_f32_16x16x32_bf16(ga01, bP1, acc0, 0, 0, 0);
        acc1 = __builtin_amdgcn_mfma_f32_16x16x32_bf16(ga10, bP0, acc1, 0, 0, 0);
        acc1 = __builtin_amdgcn_mfma_f32_16x16x32_bf16(ga11, bP1, acc1, 0, 0, 0);

        ta += 64 * CI;
        gp += 2048;
    }

    // z[m]: lanes q=0..3 share the same m
    zacc += __shfl_xor(zacc, 16);
    zacc += __shfl_xor(zacc, 32);
    if (q == 0) zpart[((size_t)ch * BB + b) * NN + m] = zacc;

    float* yp = y1part + (((size_t)ch * BB + b) * CI) * NN + m;
#pragma unroll
    for (int r = 0; r < 4; r++) {
        yp[(size_t)(4 * q + r) * NN] = acc0[r];
        yp[(size_t)(16 + 4 * q + r) * NN] = acc1[r];
    }
}

// ---------------------------------------------------------------------------
// rz: rZ[b*N+m] = 1 / sum_ch zpart
// ---------------------------------------------------------------------------
__global__ __launch_bounds__(256) void rz_kernel(
    const float* __restrict__ zpart, float* __restrict__ rZ, int NCH)
{
    int idx = blockIdx.x * 256 + threadIdx.x;   // b*NN + m
    float z = 0.f;
    for (int ch = 0; ch < NCH; ch++) z += zpart[(size_t)ch * BB * NN + idx];
    rZ[idx] = 1.f / z;
}

// ---------------------------------------------------------------------------
// scale_g2: g2s = pi-packed bf16(g2[b][c][m] * rZ[b][m])  (one elem/thread)
// ---------------------------------------------------------------------------
__global__ __launch_bounds__(256) void scale_g2_kernel(
    const ushort* __restrict__ g2, const float* __restrict__ rZ,
    ushort* __restrict__ g2s)
{
    int id = blockIdx.x * 256 + threadIdx.x;   // [0, BB*CI*NN)
    int b = id >> 17;                           // CI*NN = 1<<17
    int rem = id & ((1 << 17) - 1);
    int c = rem >> 12;                          // NN = 1<<12
    int m = rem & (NN - 1);
    float v = bf2f(g2[(size_t)b * CI * NN + (size_t)c * NN + m]) * rZ[b * NN + m];
    int mb = m >> 5, pos = inv_pi(m & 31);
    g2s[(((size_t)b * 128 + mb) * 32 + c) * 32 + pos] = f2bf(v);
}

// ---------------------------------------------------------------------------
// passB: block owns 64-n tile, streams an m-chunk.
// S'[m,n] via mfma (A=phT rows m, B=thT cols n); y2 += g2s x P' (pi k-order).
// ---------------------------------------------------------------------------
__global__ __launch_bounds__(256, 8) void passB_kernel(
    const ushort* __restrict__ thT, const ushort* __restrict__ phT,
    const ushort* __restrict__ g2s,
    float* __restrict__ y2part, int NCH)
{
    const int t = threadIdx.x;
    const int wave = t >> 6, lane = t & 63;
    const int q = lane >> 4, lm = lane & 15;
    const int b = blockIdx.y, ch = blockIdx.z;
    const int n0 = blockIdx.x * 64;
    const int n = n0 + wave * 16 + lm;
    const size_t bN = (size_t)b * NN;

    const bf16x8 bT = *(const bf16x8*)(thT + (bN + n) * CI + 8 * q);

    f32x4 acc0 = {0.f, 0.f, 0.f, 0.f};
    f32x4 acc1 = {0.f, 0.f, 0.f, 0.f};
    const f32x4 z4 = {0.f, 0.f, 0.f, 0.f};

    const int mchunk = NN / NCH;
    const int mbeg = ch * mchunk;
    const ushort* pa = phT + (bN + mbeg + lm) * CI + 8 * q;
    const ushort* gp = g2s + (((size_t)b * 128 + (mbeg >> 5)) * 32 + lm) * 32 + 8 * q;

    for (int it = 0; it < mchunk / 64; it++) {
        bf16x8 a0 = *(const bf16x8*)(pa);
        bf16x8 a1 = *(const bf16x8*)(pa + 16 * CI);
        bf16x8 a2 = *(const bf16x8*)(pa + 32 * CI);
        bf16x8 a3 = *(const bf16x8*)(pa + 48 * CI);
        bf16x8 ga00 = *(const bf16x8*)(gp);
        bf16x8 ga10 = *(const bf16x8*)(gp + 512);
        bf16x8 ga01 = *(const bf16x8*)(gp + 1024);
        bf16x8 ga11 = *(const bf16x8*)(gp + 1536);

        f32x4 d0 = __builtin_amdgcn_mfma_f32_16x16x32_bf16(a0, bT, z4, 0, 0, 0);
        f32x4 d1 = __builtin_amdgcn_mfma_f32_16x16x32_bf16(a1, bT, z4, 0, 0, 0);
        f32x4 d2 = __builtin_amdgcn_mfma_f32_16x16x32_bf16(a2, bT, z4, 0, 0, 0);
        f32x4 d3 = __builtin_amdgcn_mfma_f32_16x16x32_bf16(a3, bT, z4, 0, 0, 0);

        f32x4 p0, p1, p2, p3;
#pragma unroll
        for (int r = 0; r < 4; r++) {
            p0[r] = __builtin_amdgcn_exp2f(d0[r]);
            p1[r] = __builtin_amdgcn_exp2f(d1[r]);
            p2[r] = __builtin_amdgcn_exp2f(d2[r]);
            p3[r] = __builtin_amdgcn_exp2f(d3[r]);
        }

        bf16x8 bP0 = mk8(pk2(p0[0], p0[1]), pk2(p0[2], p0[3]),
                         pk2(p1[0], p1[1]), pk2(p1[2], p1[3]));
        bf16x8 bP1 = mk8(pk2(p2[0], p2[1]), pk2(p2[2], p2[3]),
                         pk2(p3[0], p3[1]), pk2(p3[2], p3[3]));

        acc0 = __builtin_amdgcn_mfma_f32_16x16x32_bf16(ga00, bP0, acc0, 0, 0, 0);
        acc0 = __builtin_amdgcn_mfma_f32_16x16x32_bf16(ga01, bP1, acc0, 0, 0, 0);
        acc1 = __builtin_amdgcn_mfma_f32_16x16x32_bf16(ga10, bP0, acc1, 0, 0, 0);
        acc1 = __builtin_amdgcn_mfma_f32_16x16x32_bf16(ga11, bP1, acc1, 0, 0, 0);

        pa += 64 * CI;
        gp += 2048;
    }

    float* yp = y2part + (((size_t)ch * BB + b) * CI) * NN + n;
#pragma unroll
    for (int r = 0; r < 4; r++) {
        yp[(size_t)(4 * q + r) * NN] = acc0[r];
        yp[(size_t)(16 + 4 * q + r) * NN] = acc1[r];
    }
}

// ---------------------------------------------------------------------------
// reduce: y1r = (sum_ch y1p) * rZ ; y2r = sum_ch y2p   (float4 per thread)
// ---------------------------------------------------------------------------
__global__ __launch_bounds__(256) void reduce_kernel(
    const float* __restrict__ y1p, const float* __restrict__ y2p,
    const float* __restrict__ rZ,
    float* __restrict__ y1r, float* __restrict__ y2r, int NCH)
{
    int id = blockIdx.x * 256 + threadIdx.x;    // [0, 2*BB*CI*NN/4)
    int job = id >> 17;                         // BB*CI*NN/4 = 1<<17
    int f4 = id & ((1 << 17) - 1);
    int b = f4 >> 15;                           // CI*NN/4 = 1<<15
    int rem = f4 & ((1 << 15) - 1);
    int c = rem >> 10;                          // NN/4 = 1<<10
    int j4 = rem & 1023;

    const float* part = job ? y2p : y1p;
    size_t off = ((size_t)b * CI + c) * NN + (size_t)j4 * 4;
    float4 s = {0.f, 0.f, 0.f, 0.f};
    for (int ch = 0; ch < NCH; ch++) {
        float4 v = *(const float4*)(part + (size_t)ch * BB * CI * NN + off);
        s.x += v.x; s.y += v.y; s.z += v.z; s.w += v.w;
    }
    if (job == 0) {
        float4 r = *(const float4*)(rZ + (size_t)b * NN + (size_t)j4 * 4);
        s.x *= r.x; s.y *= r.y; s.z *= r.z; s.w *= r.w;
    }
    *(float4*)((job ? y2r : y1r) + off) = s;
}

// ---------------------------------------------------------------------------
// epilogue: out = x + BN(conv1x1(y)).  grid (BB*NN/256, 2 jobs, 4 oo-slices)
// ---------------------------------------------------------------------------
__global__ __launch_bounds__(256) void epilogue_kernel(
    const float* __restrict__ x1, const float* __restrict__ x2,
    const float* __restrict__ ww, const float* __restrict__ wb,
    const float* __restrict__ wga, const float* __restrict__ wbe,
    const float* __restrict__ wmu, const float* __restrict__ wva,
    const float* __restrict__ y1r, const float* __restrict__ y2r,
    float* __restrict__ out)
{
    int job = blockIdx.y;
    int slice = blockIdx.z;                    // oo in [slice*16, slice*16+16)
    const float* yr = job ? y2r : y1r;
    const float* x = job ? x2 : x1;
    float* o = out + (size_t)job * (BB * CC * NN);

    __shared__ __align__(16) float s_w[16][CI];
    __shared__ float s_bias[16];
    int t = threadIdx.x;
    if (t < 16) {
        int oo = slice * 16 + t;
        float sc = wga[oo] / sqrtf(wva[oo] + EPS);
        s_bias[t] = wbe[oo] - wmu[oo] * sc + wb[oo] * sc;
    }
    for (int i = t; i < 16 * CI; i += 256) {
        int k = i / CI, c = i % CI;
        int oo = slice * 16 + k;
        float sc = wga[oo] / sqrtf(wva[oo] + EPS);
        s_w[k][c] = ww[oo * CI + c] * sc;
    }
    __syncthreads();

    int idx = blockIdx.x * 256 + t;
    int b = idx >> 12, j = idx & (NN - 1);

    float y[CI];
    const float* yp = yr + ((size_t)b * CI) * NN + j;
#pragma unroll
    for (int c = 0; c < CI; c++) y[c] = yp[(size_t)c * NN];

    const float* xp = x + ((size_t)b * CC + slice * 16) * NN + j;
    float* op = o + ((size_t)b * CC + slice * 16) * NN + j;
#pragma unroll
    for (int k = 0; k < 16; k++) {
        float acc = s_bias[k];
#pragma unroll
        for (int c4 = 0; c4 < CI / 4; c4++) {
            float4 wv = *(const float4*)&s_w[k][c4 * 4];
            acc += wv.x * y[c4 * 4] + wv.y * y[c4 * 4 + 1]
                 + wv.z * y[c4 * 4 + 2] + wv.w * y[c4 * 4 + 3];
        }
        op[(size_t)k * NN] = xp[(size_t)k * NN] + acc;
    }
}

// ---------------------------------------------------------------------------
extern "C" void kernel_launch(void* const* d_in, const int* in_sizes, int n_in,
                              void* d_out, int out_size, void* d_ws, size_t ws_size,
                              hipStream_t stream)
{
    const float* x1  = (const float*)d_in[0];
    const float* x2  = (const float*)d_in[1];
    const float* gw  = (const float*)d_in[2];
    const float* gb  = (const float*)d_in[3];
    const float* gga = (const float*)d_in[4];
    const float* gbe = (const float*)d_in[5];
    const float* gmu = (const float*)d_in[6];
    const float* gva = (const float*)d_in[7];
    const float* tw  = (const float*)d_in[8];
    const float* tb  = (const float*)d_in[9];
    const float* tga = (const float*)d_in[10];
    const float* tbe = (const float*)d_in[11];
    const float* tmu = (const float*)d_in[12];
    const float* tva = (const float*)d_in[13];
    const float* pw  = (const float*)d_in[14];
    const float* pb  = (const float*)d_in[15];
    const float* pga = (const float*)d_in[16];
    const float* pbe = (const float*)d_in[17];
    const float* pmu = (const float*)d_in[18];
    const float* pva = (const float*)d_in[19];
    const float* ww  = (const float*)d_in[20];
    const float* wb  = (const float*)d_in[21];
    const float* wga = (const float*)d_in[22];
    const float* wbe = (const float*)d_in[23];
    const float* wmu = (const float*)d_in[24];
    const float* wva = (const float*)d_in[25];

    int NC = 8;
    while (NC > 1) {
        size_t need = 5ull * PROJ_SZ * 2                 // bf16 proj buffers
                    + (size_t)NC * BB * NN * 4           // zpart
                    + (size_t)BB * NN * 4                // rZ
                    + 2ull * NC * BB * CI * NN * 4       // y1p + y2p
                    + 2ull * BB * CI * NN * 4;           // y1r + y2r
        if (need <= ws_size) break;
        NC >>= 1;
    }

    ushort* g1p  = (ushort*)d_ws;
    ushort* g2   = g1p + PROJ_SZ;
    ushort* g2s  = g2 + PROJ_SZ;
    ushort* thT  = g2s + PROJ_SZ;
    ushort* phT  = thT + PROJ_SZ;
    float* zpart = (float*)(phT + PROJ_SZ);
    float* rZ    = zpart + (size_t)NC * BB * NN;
    float* y1p   = rZ + (size_t)BB * NN;
    float* y2p   = y1p + (size_t)NC * BB * CI * NN;
    float* y1r   = y2p + (size_t)NC * BB * CI * NN;
    float* y2r   = y1r + (size_t)BB * CI * NN;

    proj_kernel<<<dim3(BB * NN / 256, 4), 256, 0, stream>>>(
        x1, x2, gw, gb, gga, gbe, gmu, gva, tw, tb, tga, tbe, tmu, tva,
        pw, pb, pga, pbe, pmu, pva, g1p, g2, thT, phT);

    passA_kernel<<<dim3(NN / 64, BB, NC), 256, 0, stream>>>(
        thT, phT, g1p, zpart, y1p, NC);

    rz_kernel<<<dim3(BB * NN / 256), 256, 0, stream>>>(zpart, rZ, NC);

    scale_g2_kernel<<<dim3(BB * CI * NN / 256), 256, 0, stream>>>(g2, rZ, g2s);

    passB_kernel<<<dim3(NN / 64, BB, NC), 256, 0, stream>>>(
        thT, phT, g2s, y2p, NC);

    reduce_kernel<<<dim3(2 * BB * CI * NN / 4 / 256), 256, 0, stream>>>(
        y1p, y2p, rZ, y1r, y2r, NC);

    epilogue_kernel<<<dim3(BB * NN / 256, 2, 4), 256, 0, stream>>>(
        x1, x2, ww, wb, wga, wbe, wmu, wva, y1r, y2r, (float*)d_out);
}

// Round 12
// 218.000 us; speedup vs baseline: 1.4574x; 1.0034x over previous
//
#include <hip/hip_runtime.h>
#include <math.h>

#define BB 4
#define CC 64
#define CI 32
#define NN 4096
#define EPS 1e-5f

#define PROJ_SZ (BB * CI * NN) /* 524288 elems */

typedef __attribute__((ext_vector_type(8))) short bf16x8;
typedef __attribute__((ext_vector_type(4))) float f32x4;

// f32 -> bf16 with round-to-nearest-even (raw-bit math; finite inputs only)
__device__ __forceinline__ ushort f2bf(float f) {
    uint u = __builtin_bit_cast(uint, f);
    u += 0x7FFFu + ((u >> 16) & 1u);
    return (ushort)(u >> 16);
}
__device__ __forceinline__ float bf2f(ushort h) {
    uint u = (uint)h << 16;
    return __builtin_bit_cast(float, u);
}
// packed {bf16(a), bf16(b)} via the HW instruction (no builtin on gfx950)
__device__ __forceinline__ uint pk2(float a, float b) {
    uint r;
    asm("v_cvt_pk_bf16_f32 %0, %1, %2" : "=v"(r) : "v"(a), "v"(b));
    return r;
}
__device__ __forceinline__ bf16x8 mk8(uint a, uint b, uint c, uint d) {
    uint4 u; u.x = a; u.y = b; u.z = c; u.w = d;
    return __builtin_bit_cast(bf16x8, u);
}
// pi permutation: k-slot -> n offset within 32-block (see passA packing)
// pi(8q+e) = 4q + (e&3) + 16*(e>>2)
// inv:  pos(r) = 8*((r&15)>>2) + (r&3) + 4*(r>>4)
__device__ __forceinline__ int inv_pi(int r) {
    return 8 * ((r & 15) >> 2) + (r & 3) + 4 * (r >> 4);
}

// ---------------------------------------------------------------------------
// proj: BN -> 1x1 conv, emits bf16.
// job 0: g(x1)->g1p  pi-packed [b][nb(128)][c(32)][pos(32)]
// job 1: g(x2)->g2   [b][c][n]
// job 2: th(x1)->thT [b][n][CI]  (scaled by log2(e) so exp(S)=exp2(S'))
// job 3: ph(x2)->phT [b][m][CI]
// ---------------------------------------------------------------------------
__global__ __launch_bounds__(256) void proj_kernel(
    const float* __restrict__ x1, const float* __restrict__ x2,
    const float* __restrict__ gw, const float* __restrict__ gb,
    const float* __restrict__ gga, const float* __restrict__ gbe,
    const float* __restrict__ gmu, const float* __restrict__ gva,
    const float* __restrict__ tw, const float* __restrict__ tb,
    const float* __restrict__ tga, const float* __restrict__ tbe,
    const float* __restrict__ tmu, const float* __restrict__ tva,
    const float* __restrict__ pw, const float* __restrict__ pb,
    const float* __restrict__ pga, const float* __restrict__ pbe,
    const float* __restrict__ pmu, const float* __restrict__ pva,
    ushort* __restrict__ g1p, ushort* __restrict__ g2o,
    ushort* __restrict__ thTo, ushort* __restrict__ phTo)
{
    int job = blockIdx.y;
    const float* src = (job == 0 || job == 2) ? x1 : x2;
    const float *w, *bia, *ga, *be, *mu, *va;
    if (job <= 1)      { w = gw; bia = gb; ga = gga; be = gbe; mu = gmu; va = gva; }
    else if (job == 2) { w = tw; bia = tb; ga = tga; be = tbe; mu = tmu; va = tva; }
    else               { w = pw; bia = pb; ga = pga; be = pbe; mu = pmu; va = pva; }

    __shared__ __align__(16) float s_w[CI][CC];
    __shared__ float s_scale[CC], s_shift[CC], s_b[CI];
    int t = threadIdx.x;
    if (t < CC) {
        float sc = ga[t] / sqrtf(va[t] + EPS);
        s_scale[t] = sc;
        s_shift[t] = be[t] - mu[t] * sc;
    }
    if (t >= CC && t < CC + CI) s_b[t - CC] = bia[t - CC];
    for (int i = t; i < CI * CC; i += 256) s_w[i / CC][i % CC] = w[i];
    __syncthreads();

    int bn = blockIdx.x * 256 + t;
    int b = bn >> 12, n = bn & (NN - 1);
    const float* xp = src + ((size_t)b * CC) * NN + n;

    float acc[CI];
#pragma unroll
    for (int o = 0; o < CI; o++) acc[o] = s_b[o];

#pragma unroll 4
    for (int c4 = 0; c4 < CC / 4; c4++) {
        float xv0 = xp[(size_t)(c4 * 4 + 0) * NN] * s_scale[c4 * 4 + 0] + s_shift[c4 * 4 + 0];
        float xv1 = xp[(size_t)(c4 * 4 + 1) * NN] * s_scale[c4 * 4 + 1] + s_shift[c4 * 4 + 1];
        float xv2 = xp[(size_t)(c4 * 4 + 2) * NN] * s_scale[c4 * 4 + 2] + s_shift[c4 * 4 + 2];
        float xv3 = xp[(size_t)(c4 * 4 + 3) * NN] * s_scale[c4 * 4 + 3] + s_shift[c4 * 4 + 3];
#pragma unroll
        for (int o = 0; o < CI; o++) {
            float4 wv = *(const float4*)&s_w[o][c4 * 4];
            acc[o] += wv.x * xv0 + wv.y * xv1 + wv.z * xv2 + wv.w * xv3;
        }
    }

    if (job == 0) {
        // pi-packed: g1p[((b*128 + nb)*32 + c)*32 + pos], pos = inv_pi(n&31)
        int nb = n >> 5, pos = inv_pi(n & 31);
        ushort* dp = g1p + (((size_t)b * 128 + nb) * 32) * 32 + pos;
#pragma unroll
        for (int o = 0; o < CI; o++) dp[o * 32] = f2bf(acc[o]);
    } else if (job == 1) {
        ushort* dp = g2o + ((size_t)b * CI) * NN + n;
#pragma unroll
        for (int o = 0; o < CI; o++) dp[(size_t)o * NN] = f2bf(acc[o]);
    } else {
        if (job == 2) {
#pragma unroll
            for (int o = 0; o < CI; o++) acc[o] *= 1.44269504f;  // log2(e)
        }
        uint u[16];
#pragma unroll
        for (int i = 0; i < 16; i++)
            u[i] = (uint)f2bf(acc[2 * i]) | ((uint)f2bf(acc[2 * i + 1]) << 16);
        uint4* dp = (uint4*)((job == 2 ? thTo : phTo) + ((size_t)b * NN + n) * CI);
#pragma unroll
        for (int i = 0; i < 4; i++) {
            uint4 v; v.x = u[4 * i]; v.y = u[4 * i + 1]; v.z = u[4 * i + 2]; v.w = u[4 * i + 3];
            dp[i] = v;
        }
    }
}

// ---------------------------------------------------------------------------
// passA: block owns 64-m tile (wave w -> m-subtile w), streams an n-chunk.
// S[n,m] via mfma 16x16x32. P=exp2(S) processed in TWO HALF-PHASES so the
// 16 P-values are never all live at once (fits the 64-VGPR / 8-wave cap).
// PV uses pi-permuted k-order: B-operand is the lane's own packed P values,
// A-operand (g1p) is a single coalesced 16B load per frag.
// ---------------------------------------------------------------------------
__global__ __launch_bounds__(256, 8) void passA_kernel(
    const ushort* __restrict__ thT, const ushort* __restrict__ phT,
    const ushort* __restrict__ g1p,
    float* __restrict__ zpart, float* __restrict__ y1part, int NCH)
{
    const int t = threadIdx.x;
    const int wave = t >> 6, lane = t & 63;
    const int q = lane >> 4, lm = lane & 15;
    const int b = blockIdx.y, ch = blockIdx.z;
    const int m0 = blockIdx.x * 64;
    const int m = m0 + wave * 16 + lm;
    const size_t bN = (size_t)b * NN;

    // S B-frag (phT), invariant over n: B[k=c][j=m]
    const bf16x8 bS = *(const bf16x8*)(phT + (bN + m) * CI + 8 * q);

    f32x4 acc0 = {0.f, 0.f, 0.f, 0.f};
    f32x4 acc1 = {0.f, 0.f, 0.f, 0.f};
    const f32x4 z4 = {0.f, 0.f, 0.f, 0.f};
    float zacc = 0.f;

    const int nchunk = NN / NCH;
    const int nbeg = ch * nchunk;
    const ushort* ta = thT + (bN + nbeg + lm) * CI + 8 * q;
    const ushort* gp = g1p + (((size_t)b * 128 + (nbeg >> 5)) * 32 + lm) * 32 + 8 * q;

    for (int it = 0; it < nchunk / 64; it++) {
        bf16x8 a0 = *(const bf16x8*)(ta);
        bf16x8 a1 = *(const bf16x8*)(ta + 16 * CI);
        bf16x8 a2 = *(const bf16x8*)(ta + 32 * CI);
        bf16x8 a3 = *(const bf16x8*)(ta + 48 * CI);
        bf16x8 ga00 = *(const bf16x8*)(gp);           // c=lm,    n-block 0
        bf16x8 ga10 = *(const bf16x8*)(gp + 512);     // c=16+lm, n-block 0
        bf16x8 ga01 = *(const bf16x8*)(gp + 1024);    // c=lm,    n-block 1
        bf16x8 ga11 = *(const bf16x8*)(gp + 1536);    // c=16+lm, n-block 1

        f32x4 d0 = __builtin_amdgcn_mfma_f32_16x16x32_bf16(a0, bS, z4, 0, 0, 0);
        f32x4 d1 = __builtin_amdgcn_mfma_f32_16x16x32_bf16(a1, bS, z4, 0, 0, 0);
        f32x4 d2 = __builtin_amdgcn_mfma_f32_16x16x32_bf16(a2, bS, z4, 0, 0, 0);
        f32x4 d3 = __builtin_amdgcn_mfma_f32_16x16x32_bf16(a3, bS, z4, 0, 0, 0);

        // ---- half-phase 0: (d0,d1) -> bP0 -> PV, then registers die ----
        {
            float p00 = __builtin_amdgcn_exp2f(d0[0]), p01 = __builtin_amdgcn_exp2f(d0[1]);
            float p02 = __builtin_amdgcn_exp2f(d0[2]), p03 = __builtin_amdgcn_exp2f(d0[3]);
            float p10 = __builtin_amdgcn_exp2f(d1[0]), p11 = __builtin_amdgcn_exp2f(d1[1]);
            float p12 = __builtin_amdgcn_exp2f(d1[2]), p13 = __builtin_amdgcn_exp2f(d1[3]);
            zacc += ((p00 + p01) + (p02 + p03)) + ((p10 + p11) + (p12 + p13));
            bf16x8 bP0 = mk8(pk2(p00, p01), pk2(p02, p03),
                             pk2(p10, p11), pk2(p12, p13));
            acc0 = __builtin_amdgcn_mfma_f32_16x16x32_bf16(ga00, bP0, acc0, 0, 0, 0);
            acc1 = __builtin_amdgcn_mfma_f32_16x16x32_bf16(ga10, bP0, acc1, 0, 0, 0);
        }
        // ---- half-phase 1: (d2,d3) -> bP1 -> PV ----
        {
            float p20 = __builtin_amdgcn_exp2f(d2[0]), p21 = __builtin_amdgcn_exp2f(d2[1]);
            float p22 = __builtin_amdgcn_exp2f(d2[2]), p23 = __builtin_amdgcn_exp2f(d2[3]);
            float p30 = __builtin_amdgcn_exp2f(d3[0]), p31 = __builtin_amdgcn_exp2f(d3[1]);
            float p32 = __builtin_amdgcn_exp2f(d3[2]), p33 = __builtin_amdgcn_exp2f(d3[3]);
            zacc += ((p20 + p21) + (p22 + p23)) + ((p30 + p31) + (p32 + p33));
            bf16x8 bP1 = mk8(pk2(p20, p21), pk2(p22, p23),
                             pk2(p30, p31), pk2(p32, p33));
            acc0 = __builtin_amdgcn_mfma_f32_16x16x32_bf16(ga01, bP1, acc0, 0, 0, 0);
            acc1 = __builtin_amdgcn_mfma_f32_16x16x32_bf16(ga11, bP1, acc1, 0, 0, 0);
        }

        ta += 64 * CI;
        gp += 2048;
    }

    // z[m]: lanes q=0..3 share the same m
    zacc += __shfl_xor(zacc, 16);
    zacc += __shfl_xor(zacc, 32);
    if (q == 0) zpart[((size_t)ch * BB + b) * NN + m] = zacc;

    float* yp = y1part + (((size_t)ch * BB + b) * CI) * NN + m;
#pragma unroll
    for (int r = 0; r < 4; r++) {
        yp[(size_t)(4 * q + r) * NN] = acc0[r];
        yp[(size_t)(16 + 4 * q + r) * NN] = acc1[r];
    }
}

// ---------------------------------------------------------------------------
// rz: rZ[b*N+m] = 1 / sum_ch zpart
// ---------------------------------------------------------------------------
__global__ __launch_bounds__(256) void rz_kernel(
    const float* __restrict__ zpart, float* __restrict__ rZ, int NCH)
{
    int idx = blockIdx.x * 256 + threadIdx.x;   // b*NN + m
    float z = 0.f;
    for (int ch = 0; ch < NCH; ch++) z += zpart[(size_t)ch * BB * NN + idx];
    rZ[idx] = 1.f / z;
}

// ---------------------------------------------------------------------------
// scale_g2: g2s = pi-packed bf16(g2[b][c][m] * rZ[b][m])  (one elem/thread)
// ---------------------------------------------------------------------------
__global__ __launch_bounds__(256) void scale_g2_kernel(
    const ushort* __restrict__ g2, const float* __restrict__ rZ,
    ushort* __restrict__ g2s)
{
    int id = blockIdx.x * 256 + threadIdx.x;   // [0, BB*CI*NN)
    int b = id >> 17;                           // CI*NN = 1<<17
    int rem = id & ((1 << 17) - 1);
    int c = rem >> 12;                          // NN = 1<<12
    int m = rem & (NN - 1);
    float v = bf2f(g2[(size_t)b * CI * NN + (size_t)c * NN + m]) * rZ[b * NN + m];
    int mb = m >> 5, pos = inv_pi(m & 31);
    g2s[(((size_t)b * 128 + mb) * 32 + c) * 32 + pos] = f2bf(v);
}

// ---------------------------------------------------------------------------
// passB: block owns 64-n tile, streams an m-chunk. Same half-phase structure.
// ---------------------------------------------------------------------------
__global__ __launch_bounds__(256, 8) void passB_kernel(
    const ushort* __restrict__ thT, const ushort* __restrict__ phT,
    const ushort* __restrict__ g2s,
    float* __restrict__ y2part, int NCH)
{
    const int t = threadIdx.x;
    const int wave = t >> 6, lane = t & 63;
    const int q = lane >> 4, lm = lane & 15;
    const int b = blockIdx.y, ch = blockIdx.z;
    const int n0 = blockIdx.x * 64;
    const int n = n0 + wave * 16 + lm;
    const size_t bN = (size_t)b * NN;

    const bf16x8 bT = *(const bf16x8*)(thT + (bN + n) * CI + 8 * q);

    f32x4 acc0 = {0.f, 0.f, 0.f, 0.f};
    f32x4 acc1 = {0.f, 0.f, 0.f, 0.f};
    const f32x4 z4 = {0.f, 0.f, 0.f, 0.f};

    const int mchunk = NN / NCH;
    const int mbeg = ch * mchunk;
    const ushort* pa = phT + (bN + mbeg + lm) * CI + 8 * q;
    const ushort* gp = g2s + (((size_t)b * 128 + (mbeg >> 5)) * 32 + lm) * 32 + 8 * q;

    for (int it = 0; it < mchunk / 64; it++) {
        bf16x8 a0 = *(const bf16x8*)(pa);
        bf16x8 a1 = *(const bf16x8*)(pa + 16 * CI);
        bf16x8 a2 = *(const bf16x8*)(pa + 32 * CI);
        bf16x8 a3 = *(const bf16x8*)(pa + 48 * CI);
        bf16x8 ga00 = *(const bf16x8*)(gp);
        bf16x8 ga10 = *(const bf16x8*)(gp + 512);
        bf16x8 ga01 = *(const bf16x8*)(gp + 1024);
        bf16x8 ga11 = *(const bf16x8*)(gp + 1536);

        f32x4 d0 = __builtin_amdgcn_mfma_f32_16x16x32_bf16(a0, bT, z4, 0, 0, 0);
        f32x4 d1 = __builtin_amdgcn_mfma_f32_16x16x32_bf16(a1, bT, z4, 0, 0, 0);
        f32x4 d2 = __builtin_amdgcn_mfma_f32_16x16x32_bf16(a2, bT, z4, 0, 0, 0);
        f32x4 d3 = __builtin_amdgcn_mfma_f32_16x16x32_bf16(a3, bT, z4, 0, 0, 0);

        {
            float p00 = __builtin_amdgcn_exp2f(d0[0]), p01 = __builtin_amdgcn_exp2f(d0[1]);
            float p02 = __builtin_amdgcn_exp2f(d0[2]), p03 = __builtin_amdgcn_exp2f(d0[3]);
            float p10 = __builtin_amdgcn_exp2f(d1[0]), p11 = __builtin_amdgcn_exp2f(d1[1]);
            float p12 = __builtin_amdgcn_exp2f(d1[2]), p13 = __builtin_amdgcn_exp2f(d1[3]);
            bf16x8 bP0 = mk8(pk2(p00, p01), pk2(p02, p03),
                             pk2(p10, p11), pk2(p12, p13));
            acc0 = __builtin_amdgcn_mfma_f32_16x16x32_bf16(ga00, bP0, acc0, 0, 0, 0);
            acc1 = __builtin_amdgcn_mfma_f32_16x16x32_bf16(ga10, bP0, acc1, 0, 0, 0);
        }
        {
            float p20 = __builtin_amdgcn_exp2f(d2[0]), p21 = __builtin_amdgcn_exp2f(d2[1]);
            float p22 = __builtin_amdgcn_exp2f(d2[2]), p23 = __builtin_amdgcn_exp2f(d2[3]);
            float p30 = __builtin_amdgcn_exp2f(d3[0]), p31 = __builtin_amdgcn_exp2f(d3[1]);
            float p32 = __builtin_amdgcn_exp2f(d3[2]), p33 = __builtin_amdgcn_exp2f(d3[3]);
            bf16x8 bP1 = mk8(pk2(p20, p21), pk2(p22, p23),
                             pk2(p30, p31), pk2(p32, p33));
            acc0 = __builtin_amdgcn_mfma_f32_16x16x32_bf16(ga01, bP1, acc0, 0, 0, 0);
            acc1 = __builtin_amdgcn_mfma_f32_16x16x32_bf16(ga11, bP1, acc1, 0, 0, 0);
        }

        pa += 64 * CI;
        gp += 2048;
    }

    float* yp = y2part + (((size_t)ch * BB + b) * CI) * NN + n;
#pragma unroll
    for (int r = 0; r < 4; r++) {
        yp[(size_t)(4 * q + r) * NN] = acc0[r];
        yp[(size_t)(16 + 4 * q + r) * NN] = acc1[r];
    }
}

// ---------------------------------------------------------------------------
// reduce: y1r = (sum_ch y1p) * rZ ; y2r = sum_ch y2p   (float4 per thread)
// ---------------------------------------------------------------------------
__global__ __launch_bounds__(256) void reduce_kernel(
    const float* __restrict__ y1p, const float* __restrict__ y2p,
    const float* __restrict__ rZ,
    float* __restrict__ y1r, float* __restrict__ y2r, int NCH)
{
    int id = blockIdx.x * 256 + threadIdx.x;    // [0, 2*BB*CI*NN/4)
    int job = id >> 17;                         // BB*CI*NN/4 = 1<<17
    int f4 = id & ((1 << 17) - 1);
    int b = f4 >> 15;                           // CI*NN/4 = 1<<15
    int rem = f4 & ((1 << 15) - 1);
    int c = rem >> 10;                          // NN/4 = 1<<10
    int j4 = rem & 1023;

    const float* part = job ? y2p : y1p;
    size_t off = ((size_t)b * CI + c) * NN + (size_t)j4 * 4;
    float4 s = {0.f, 0.f, 0.f, 0.f};
    for (int ch = 0; ch < NCH; ch++) {
        float4 v = *(const float4*)(part + (size_t)ch * BB * CI * NN + off);
        s.x += v.x; s.y += v.y; s.z += v.z; s.w += v.w;
    }
    if (job == 0) {
        float4 r = *(const float4*)(rZ + (size_t)b * NN + (size_t)j4 * 4);
        s.x *= r.x; s.y *= r.y; s.z *= r.z; s.w *= r.w;
    }
    *(float4*)((job ? y2r : y1r) + off) = s;
}

// ---------------------------------------------------------------------------
// epilogue: out = x + BN(conv1x1(y)).  grid (BB*NN/256, 2 jobs, 4 oo-slices)
// ---------------------------------------------------------------------------
__global__ __launch_bounds__(256) void epilogue_kernel(
    const float* __restrict__ x1, const float* __restrict__ x2,
    const float* __restrict__ ww, const float* __restrict__ wb,
    const float* __restrict__ wga, const float* __restrict__ wbe,
    const float* __restrict__ wmu, const float* __restrict__ wva,
    const float* __restrict__ y1r, const float* __restrict__ y2r,
    float* __restrict__ out)
{
    int job = blockIdx.y;
    int slice = blockIdx.z;                    // oo in [slice*16, slice*16+16)
    const float* yr = job ? y2r : y1r;
    const float* x = job ? x2 : x1;
    float* o = out + (size_t)job * (BB * CC * NN);

    __shared__ __align__(16) float s_w[16][CI];
    __shared__ float s_bias[16];
    int t = threadIdx.x;
    if (t < 16) {
        int oo = slice * 16 + t;
        float sc = wga[oo] / sqrtf(wva[oo] + EPS);
        s_bias[t] = wbe[oo] - wmu[oo] * sc + wb[oo] * sc;
    }
    for (int i = t; i < 16 * CI; i += 256) {
        int k = i / CI, c = i % CI;
        int oo = slice * 16 + k;
        float sc = wga[oo] / sqrtf(wva[oo] + EPS);
        s_w[k][c] = ww[oo * CI + c] * sc;
    }
    __syncthreads();

    int idx = blockIdx.x * 256 + t;
    int b = idx >> 12, j = idx & (NN - 1);

    float y[CI];
    const float* yp = yr + ((size_t)b * CI) * NN + j;
#pragma unroll
    for (int c = 0; c < CI; c++) y[c] = yp[(size_t)c * NN];

    const float* xp = x + ((size_t)b * CC + slice * 16) * NN + j;
    float* op = o + ((size_t)b * CC + slice * 16) * NN + j;
#pragma unroll
    for (int k = 0; k < 16; k++) {
        float acc = s_bias[k];
#pragma unroll
        for (int c4 = 0; c4 < CI / 4; c4++) {
            float4 wv = *(const float4*)&s_w[k][c4 * 4];
            acc += wv.x * y[c4 * 4] + wv.y * y[c4 * 4 + 1]
                 + wv.z * y[c4 * 4 + 2] + wv.w * y[c4 * 4 + 3];
        }
        op[(size_t)k * NN] = xp[(size_t)k * NN] + acc;
    }
}

// ---------------------------------------------------------------------------
extern "C" void kernel_launch(void* const* d_in, const int* in_sizes, int n_in,
                              void* d_out, int out_size, void* d_ws, size_t ws_size,
                              hipStream_t stream)
{
    const float* x1  = (const float*)d_in[0];
    const float* x2  = (const float*)d_in[1];
    const float* gw  = (const float*)d_in[2];
    const float* gb  = (const float*)d_in[3];
    const float* gga = (const float*)d_in[4];
    const float* gbe = (const float*)d_in[5];
    const float* gmu = (const float*)d_in[6];
    const float* gva = (const float*)d_in[7];
    const float* tw  = (const float*)d_in[8];
    const float* tb  = (const float*)d_in[9];
    const float* tga = (const float*)d_in[10];
    const float* tbe = (const float*)d_in[11];
    const float* tmu = (const float*)d_in[12];
    const float* tva = (const float*)d_in[13];
    const float* pw  = (const float*)d_in[14];
    const float* pb  = (const float*)d_in[15];
    const float* pga = (const float*)d_in[16];
    const float* pbe = (const float*)d_in[17];
    const float* pmu = (const float*)d_in[18];
    const float* pva = (const float*)d_in[19];
    const float* ww  = (const float*)d_in[20];
    const float* wb  = (const float*)d_in[21];
    const float* wga = (const float*)d_in[22];
    const float* wbe = (const float*)d_in[23];
    const float* wmu = (const float*)d_in[24];
    const float* wva = (const float*)d_in[25];

    int NC = 8;
    while (NC > 1) {
        size_t need = 5ull * PROJ_SZ * 2                 // bf16 proj buffers
                    + (size_t)NC * BB * NN * 4           // zpart
                    + (size_t)BB * NN * 4                // rZ
                    + 2ull * NC * BB * CI * NN * 4       // y1p + y2p
                    + 2ull * BB * CI * NN * 4;           // y1r + y2r
        if (need <= ws_size) break;
        NC >>= 1;
    }

    ushort* g1p  = (ushort*)d_ws;
    ushort* g2   = g1p + PROJ_SZ;
    ushort* g2s  = g2 + PROJ_SZ;
    ushort* thT  = g2s + PROJ_SZ;
    ushort* phT  = thT + PROJ_SZ;
    float* zpart = (float*)(phT + PROJ_SZ);
    float* rZ    = zpart + (size_t)NC * BB * NN;
    float* y1p   = rZ + (size_t)BB * NN;
    float* y2p   = y1p + (size_t)NC * BB * CI * NN;
    float* y1r   = y2p + (size_t)NC * BB * CI * NN;
    float* y2r   = y1r + (size_t)BB * CI * NN;

    proj_kernel<<<dim3(BB * NN / 256, 4), 256, 0, stream>>>(
        x1, x2, gw, gb, gga, gbe, gmu, gva, tw, tb, tga, tbe, tmu, tva,
        pw, pb, pga, pbe, pmu, pva, g1p, g2, thT, phT);

    passA_kernel<<<dim3(NN / 64, BB, NC), 256, 0, stream>>>(
        thT, phT, g1p, zpart, y1p, NC);

    rz_kernel<<<dim3(BB * NN / 256), 256, 0, stream>>>(zpart, rZ, NC);

    scale_g2_kernel<<<dim3(BB * CI * NN / 256), 256, 0, stream>>>(g2, rZ, g2s);

    passB_kernel<<<dim3(NN / 64, BB, NC), 256, 0, stream>>>(
        thT, phT, g2s, y2p, NC);

    reduce_kernel<<<dim3(2 * BB * CI * NN / 4 / 256), 256, 0, stream>>>(
        y1p, y2p, rZ, y1r, y2r, NC);

    epilogue_kernel<<<dim3(BB * NN / 256, 2, 4), 256, 0, stream>>>(
        x1, x2, ww, wb, wga, wbe, wmu, wva, y1r, y2r, (float*)d_out);
}